// Round 1
// baseline (984.793 us; speedup 1.0000x reference)
//
#include <hip/hip_runtime.h>
#include <stdint.h>

#define H 256
#define NATOMS 100000
#define MB 16

typedef float floatx4 __attribute__((ext_vector_type(4)));
typedef short short8 __attribute__((ext_vector_type(8)));
typedef short short4v __attribute__((ext_vector_type(4)));

__device__ __forceinline__ unsigned short f2bf(float x) {
    union { float f; uint32_t u; } c; c.f = x;
    return (unsigned short)((c.u + 0x7FFFu + ((c.u >> 16) & 1u)) >> 16);
}
__device__ __forceinline__ float bf2f(unsigned short h) {
    union { uint32_t u; float f; } c; c.u = ((uint32_t)h) << 16; return c.f;
}

// ---------------------------------------------------------------------------
// Pack weights (f32 [K][N] row-major) into bf16 MFMA-B-fragment order:
// frag (kb, nb): P[(fragBase + fl)*512 + l*8 + e] = W[kb*32 + (l>>4)*8 + e][nb*16 + (l&15)]
// fl = nb*(K/32) + kb.  One 16B chunk per lane -> main kernel loads dwordx4.
// Layout in ws (bf16 elems): U@0 (128 frags), V@65536, W1@131072, W2@262144.
// ---------------------------------------------------------------------------
__global__ void pack_weights(const float* __restrict__ U_W, const float* __restrict__ V_W,
                             const float* __restrict__ W1, const float* __restrict__ W2,
                             unsigned short* __restrict__ P) {
    int gtid = blockIdx.x * 256 + threadIdx.x;
    int fid = gtid >> 6, l = gtid & 63;
    const float* src; int K, N, fl; unsigned short* dst;
    if (fid < 128)      { src = U_W; K = 256; N = 256; fl = fid;       dst = P; }
    else if (fid < 256) { src = V_W; K = 256; N = 256; fl = fid - 128; dst = P + 65536; }
    else if (fid < 512) { src = W1;  K = 512; N = 256; fl = fid - 256; dst = P + 131072; }
    else                { src = W2;  K = 256; N = 768; fl = fid - 512; dst = P + 262144; }
    int kbc = K >> 5;
    int nb = fl / kbc, kb = fl - nb * kbc;
    int k0 = kb * 32 + ((l >> 4) << 3);
    int n0 = nb * 16 + (l & 15);
    short8 outv;
#pragma unroll
    for (int e = 0; e < 8; e++) outv[e] = (short)f2bf(src[(size_t)(k0 + e) * N + n0]);
    *(short8*)(dst + (size_t)fl * 512 + l * 8) = outv;
}

// ---------------------------------------------------------------------------
// Fused PaiNN mixing: one block = 16 atoms, 256 threads (4 waves).
// ---------------------------------------------------------------------------
__global__ __launch_bounds__(256, 2) void painn_main(
    const float* __restrict__ s, const float* __restrict__ v,
    const float* __restrict__ gamma, const float* __restrict__ beta,
    const float* __restrict__ b1, const float* __restrict__ b2,
    const unsigned short* __restrict__ P,
    float* __restrict__ s_out, float* __restrict__ v_out) {

    __shared__ unsigned short A_buf[48 * 256];   // 24KB: v tile bf16 [r=d*16+a][256]; reused as ctx [16][768]
    __shared__ unsigned short ctxin[16 * 512];   // 16KB: [a][0:256]=s_normed, [256:512]=Vv_norm
    __shared__ unsigned short hid[16 * 256];     // 8KB

    const int tid = threadIdx.x;
    const int w = tid >> 6, l = tid & 63;
    const int atom0 = blockIdx.x * MB;

    // ---- phase 0a: stage v tile -> LDS bf16, swizzled ----
    {
        const floatx4* vsrc = (const floatx4*)(v + (size_t)atom0 * 3 * H);
#pragma unroll
        for (int i = 0; i < 12; i++) {
            int q = i * 256 + tid;            // float4 index, 3072 total
            int g = q >> 6, c4 = q & 63;      // g: [a][d] row, c4: float4 col chunk
            floatx4 val = vsrc[q];
            int a = g / 3, d = g - 3 * a;
            int r = d * 16 + a;
            short4v pk;
#pragma unroll
            for (int j = 0; j < 4; j++) pk[j] = (short)f2bf(val[j]);
            int bo = (r * 512 + c4 * 8) ^ ((r & 7) << 4);
            *(short4v*)((char*)A_buf + bo) = pk;
        }
    }

    // ---- phase 0b: LayerNorm(s) -> ctxin[:,0:256] bf16 ----
    {
        int a = tid >> 4, lg = tid & 15;
        const floatx4* srow = (const floatx4*)(s + (size_t)(atom0 + a) * H);
        floatx4 vals[4];
        float sum = 0.f, sumsq = 0.f;
#pragma unroll
        for (int i = 0; i < 4; i++) {
            vals[i] = srow[lg + (i << 4)];
#pragma unroll
            for (int j = 0; j < 4; j++) { sum += vals[i][j]; sumsq += vals[i][j] * vals[i][j]; }
        }
#pragma unroll
        for (int m = 1; m < 16; m <<= 1) { sum += __shfl_xor(sum, m); sumsq += __shfl_xor(sumsq, m); }
        float mu = sum * (1.f / 256.f);
        float var = sumsq * (1.f / 256.f) - mu * mu;
        float rs = rsqrtf(var + 1e-5f);
#pragma unroll
        for (int i = 0; i < 4; i++) {
            int chunk = lg + (i << 4);
            floatx4 g4 = *(const floatx4*)(gamma + chunk * 4);
            floatx4 be4 = *(const floatx4*)(beta + chunk * 4);
            short4v pk;
#pragma unroll
            for (int j = 0; j < 4; j++) pk[j] = (short)f2bf((vals[i][j] - mu) * rs * g4[j] + be4[j]);
            int bo = (a * 1024 + chunk * 8) ^ ((a & 7) << 4);
            *(short4v*)((char*)ctxin + bo) = pk;
        }
    }

    __syncthreads();

    // ---- phase 1: GEMM Uv & Vv.  A: [48 x 256] LDS; B: packed global (L2). ----
    // wave w owns cols [64w, 64w+64); acc kept in registers through the whole kernel.
    floatx4 accU[3][4], accV[3][4];
#pragma unroll
    for (int rf = 0; rf < 3; rf++)
#pragma unroll
        for (int cf = 0; cf < 4; cf++) { accU[rf][cf] = (floatx4)0.f; accV[rf][cf] = (floatx4)0.f; }

    {
        const short8* PU = (const short8*)(P);
        const short8* PV = (const short8*)(P + 65536);
        for (int ks = 0; ks < 8; ks++) {
            short8 afr[3];
#pragma unroll
            for (int rf = 0; rf < 3; rf++) {
                int r = (rf << 4) + (l & 15);
                int bo = (r * 512 + (ks << 6) + ((l >> 4) << 4)) ^ ((r & 7) << 4);
                afr[rf] = *(const short8*)((const char*)A_buf + bo);
            }
#pragma unroll
            for (int cf = 0; cf < 4; cf++) {
                int nb = (w << 2) + cf;
                short8 bU = PU[(size_t)(nb * 8 + ks) * 64 + l];
                short8 bV = PV[(size_t)(nb * 8 + ks) * 64 + l];
#pragma unroll
                for (int rf = 0; rf < 3; rf++) {
                    accU[rf][cf] = __builtin_amdgcn_mfma_f32_16x16x32_bf16(afr[rf], bU, accU[rf][cf], 0, 0, 0);
                    accV[rf][cf] = __builtin_amdgcn_mfma_f32_16x16x32_bf16(afr[rf], bV, accV[rf][cf], 0, 0, 0);
                }
            }
        }
    }

    // ---- dot_uv and ||Vv|| are thread-local (all 3 d's of a column live in this lane) ----
    float dotv[4][4];
#pragma unroll
    for (int cf = 0; cf < 4; cf++) {
#pragma unroll
        for (int j = 0; j < 4; j++) {
            dotv[cf][j] = accU[0][cf][j] * accV[0][cf][j] + accU[1][cf][j] * accV[1][cf][j]
                        + accU[2][cf][j] * accV[2][cf][j];
            float nv = sqrtf(accV[0][cf][j] * accV[0][cf][j] + accV[1][cf][j] * accV[1][cf][j]
                           + accV[2][cf][j] * accV[2][cf][j] + 1e-8f);
            int a = ((l >> 4) << 2) + j;
            int c = (w << 6) + (cf << 4) + (l & 15);
            int bo = (a * 1024 + 512 + c * 2) ^ ((a & 7) << 4);
            *(unsigned short*)((char*)ctxin + bo) = f2bf(nv);
        }
    }

    __syncthreads();

    // ---- phase 2: hidden = silu(ctx_in @ W1 + b1), M=16, K=512 ----
    {
        floatx4 acc2[4];
#pragma unroll
        for (int cf = 0; cf < 4; cf++) acc2[cf] = (floatx4)0.f;
        const short8* PW1 = (const short8*)(P + 131072);
        for (int ks = 0; ks < 16; ks++) {
            int r = l & 15;
            int bo = (r * 1024 + (ks << 6) + ((l >> 4) << 4)) ^ ((r & 7) << 4);
            short8 af = *(const short8*)((const char*)ctxin + bo);
#pragma unroll
            for (int cf = 0; cf < 4; cf++) {
                int nb = (w << 2) + cf;
                short8 bfr = PW1[(size_t)(nb * 16 + ks) * 64 + l];
                acc2[cf] = __builtin_amdgcn_mfma_f32_16x16x32_bf16(af, bfr, acc2[cf], 0, 0, 0);
            }
        }
#pragma unroll
        for (int cf = 0; cf < 4; cf++) {
            int c = (w << 6) + (cf << 4) + (l & 15);
            float bb = b1[c];
#pragma unroll
            for (int j = 0; j < 4; j++) {
                int a = ((l >> 4) << 2) + j;
                float x = acc2[cf][j] + bb;
                float hh = x / (1.f + expf(-x));
                int bo = (a * 512 + c * 2) ^ ((a & 7) << 4);
                *(unsigned short*)((char*)hid + bo) = f2bf(hh);
            }
        }
    }

    __syncthreads();

    // ---- phase 3: ctx = hidden @ W2 + b2, M=16, K=256, N=768; wave strip = 192 cols ----
    {
        floatx4 acc3[12];
#pragma unroll
        for (int cf = 0; cf < 12; cf++) acc3[cf] = (floatx4)0.f;
        const short8* PW2 = (const short8*)(P + 262144);
        for (int ks = 0; ks < 8; ks++) {
            int r = l & 15;
            int bo = (r * 512 + (ks << 6) + ((l >> 4) << 4)) ^ ((r & 7) << 4);
            short8 af = *(const short8*)((const char*)hid + bo);
#pragma unroll
            for (int cf = 0; cf < 12; cf++) {
                int nb = w * 12 + cf;
                short8 bfr = PW2[(size_t)(nb * 8 + ks) * 64 + l];
                acc3[cf] = __builtin_amdgcn_mfma_f32_16x16x32_bf16(af, bfr, acc3[cf], 0, 0, 0);
            }
        }
        // write ctx (bf16) into A_buf reused as [16][768]
#pragma unroll
        for (int cf = 0; cf < 12; cf++) {
            int c = w * 192 + (cf << 4) + (l & 15);
            float bb = b2[c];
#pragma unroll
            for (int j = 0; j < 4; j++) {
                int a = ((l >> 4) << 2) + j;
                int bo = (a * 1536 + c * 2) ^ ((a & 7) << 4);
                *(unsigned short*)((char*)A_buf + bo) = f2bf(acc3[cf][j] + bb);
            }
        }
    }

    __syncthreads();

    // ---- epilogue: s_out and v_out from register-resident Uv/dot + ctx in LDS ----
    {
        const char* ctx = (const char*)A_buf;
#pragma unroll
        for (int cf = 0; cf < 4; cf++) {
#pragma unroll
            for (int j = 0; j < 4; j++) {
                int a = ((l >> 4) << 2) + j;
                int c = (w << 6) + (cf << 4) + (l & 15);
                int rowb = a * 1536, swz = (a & 7) << 4;
                float a_ss = bf2f(*(const unsigned short*)(ctx + ((rowb + c * 2) ^ swz)));
                float a_sv = bf2f(*(const unsigned short*)(ctx + ((rowb + 512 + c * 2) ^ swz)));
                float a_vv = bf2f(*(const unsigned short*)(ctx + ((rowb + 1024 + c * 2) ^ swz)));
                size_t grow = (size_t)(atom0 + a);
                size_t gi = grow * H + c;
                s_out[gi] = s[gi] + a_ss + a_sv * dotv[cf][j];
#pragma unroll
                for (int d = 0; d < 3; d++) {
                    size_t vi = (grow * 3 + d) * (size_t)H + c;
                    v_out[vi] = v[vi] + a_vv * accU[d][cf][j];
                }
            }
        }
    }
}

extern "C" void kernel_launch(void* const* d_in, const int* in_sizes, int n_in,
                              void* d_out, int out_size, void* d_ws, size_t ws_size,
                              hipStream_t stream) {
    const float* s     = (const float*)d_in[0];
    const float* v     = (const float*)d_in[1];
    const float* gamma = (const float*)d_in[2];
    const float* beta  = (const float*)d_in[3];
    const float* U_W   = (const float*)d_in[4];
    const float* V_W   = (const float*)d_in[5];
    const float* W1    = (const float*)d_in[6];
    const float* b1    = (const float*)d_in[7];
    const float* W2    = (const float*)d_in[8];
    const float* b2    = (const float*)d_in[9];
    float* s_out = (float*)d_out;
    float* v_out = s_out + (size_t)NATOMS * H;
    unsigned short* P = (unsigned short*)d_ws;   // needs 917504 B

    pack_weights<<<dim3(224), dim3(256), 0, stream>>>(U_W, V_W, W1, W2, P);
    painn_main<<<dim3(NATOMS / MB), dim3(256), 0, stream>>>(s, v, gamma, beta, b1, b2, P, s_out, v_out);
}

// Round 2
// 447.578 us; speedup vs baseline: 2.2003x; 2.2003x over previous
//
#include <hip/hip_runtime.h>
#include <stdint.h>

#define H 256
#define NATOMS 100000
#define MB 32

typedef float floatx4 __attribute__((ext_vector_type(4)));
typedef short short8 __attribute__((ext_vector_type(8)));
typedef short short4v __attribute__((ext_vector_type(4)));

__device__ __forceinline__ unsigned short f2bf(float x) {
    union { float f; uint32_t u; } c; c.f = x;
    return (unsigned short)((c.u + 0x7FFFu + ((c.u >> 16) & 1u)) >> 16);
}
__device__ __forceinline__ float bf2f(unsigned short h) {
    union { uint32_t u; float f; } c; c.u = ((uint32_t)h) << 16; return c.f;
}

// ---------------------------------------------------------------------------
// Pack weights (f32 [K][N] row-major) into bf16 MFMA-B-fragment order:
// frag (kb, nb): P[(fragBase + fl)*512 + l*8 + e] = W[kb*32 + (l>>4)*8 + e][nb*16 + (l&15)]
// fl = nb*(K/32) + kb.
// Layout in ws (bf16 elems): U@0, V@65536, W1@131072, W2@262144.
// ---------------------------------------------------------------------------
__global__ void pack_weights(const float* __restrict__ U_W, const float* __restrict__ V_W,
                             const float* __restrict__ W1, const float* __restrict__ W2,
                             unsigned short* __restrict__ P) {
    int gtid = blockIdx.x * 256 + threadIdx.x;
    int fid = gtid >> 6, l = gtid & 63;
    const float* src; int K, N, fl; unsigned short* dst;
    if (fid < 128)      { src = U_W; K = 256; N = 256; fl = fid;       dst = P; }
    else if (fid < 256) { src = V_W; K = 256; N = 256; fl = fid - 128; dst = P + 65536; }
    else if (fid < 512) { src = W1;  K = 512; N = 256; fl = fid - 256; dst = P + 131072; }
    else                { src = W2;  K = 256; N = 768; fl = fid - 512; dst = P + 262144; }
    int kbc = K >> 5;
    int nb = fl / kbc, kb = fl - nb * kbc;
    int k0 = kb * 32 + ((l >> 4) << 3);
    int n0 = nb * 16 + (l & 15);
    short8 outv;
#pragma unroll
    for (int e = 0; e < 8; e++) outv[e] = (short)f2bf(src[(size_t)(k0 + e) * N + n0]);
    *(short8*)(dst + (size_t)fl * 512 + l * 8) = outv;
}

// ---------------------------------------------------------------------------
// Fused PaiNN mixing: one block = 32 atoms, 512 threads (8 waves).
// Wave w owns output-channel strip [32w, 32w+32).
// LDS: A_buf 48KB (v tile -> reused as hid), ctxin 32KB.  80KB total.
// ---------------------------------------------------------------------------
__global__ __launch_bounds__(512, 2) void painn_main(
    const float* __restrict__ s, const float* __restrict__ v,
    const float* __restrict__ gamma, const float* __restrict__ beta,
    const float* __restrict__ b1, const float* __restrict__ b2,
    const unsigned short* __restrict__ P,
    float* __restrict__ s_out, float* __restrict__ v_out) {

    __shared__ unsigned short A_buf[96 * 256];   // v tile [r=d*32+a][256]; later hid [32][256]
    __shared__ unsigned short ctxin[32 * 512];   // [a][0:256]=s_normed, [256:512]=Vv_norm

    const int tid = threadIdx.x;
    const int w = tid >> 6, l = tid & 63;
    const int l15 = l & 15, lhi = l >> 4;
    const int atom0 = blockIdx.x * MB;

    // ---- phase 0a: stage v tile -> LDS bf16, swizzled ----
    {
        const floatx4* vsrc = (const floatx4*)(v + (size_t)atom0 * 3 * H);
#pragma unroll
        for (int i = 0; i < 12; i++) {
            int q = i * 512 + tid;            // float4 index, 6144 total
            int g = q >> 6, c4 = q & 63;
            floatx4 val = vsrc[q];
            int a = g / 3, d = g - 3 * a;
            int r = d * 32 + a;
            short4v pk;
#pragma unroll
            for (int j = 0; j < 4; j++) pk[j] = (short)f2bf(val[j]);
            int bo = (r * 512 + c4 * 8) ^ ((r & 7) << 4);
            *(short4v*)((char*)A_buf + bo) = pk;
        }
    }

    // ---- phase 0b: LayerNorm(s) -> ctxin[:,0:256] bf16 ----
    {
        int a = tid >> 4, lg = tid & 15;
        const floatx4* srow = (const floatx4*)(s + (size_t)(atom0 + a) * H);
        floatx4 vals[4];
        float sum = 0.f, sumsq = 0.f;
#pragma unroll
        for (int i = 0; i < 4; i++) {
            vals[i] = srow[lg + (i << 4)];
#pragma unroll
            for (int j = 0; j < 4; j++) { sum += vals[i][j]; sumsq += vals[i][j] * vals[i][j]; }
        }
#pragma unroll
        for (int m = 1; m < 16; m <<= 1) { sum += __shfl_xor(sum, m); sumsq += __shfl_xor(sumsq, m); }
        float mu = sum * (1.f / 256.f);
        float var = sumsq * (1.f / 256.f) - mu * mu;
        float rs = rsqrtf(var + 1e-5f);
#pragma unroll
        for (int i = 0; i < 4; i++) {
            int chunk = lg + (i << 4);
            floatx4 g4 = *(const floatx4*)(gamma + chunk * 4);
            floatx4 be4 = *(const floatx4*)(beta + chunk * 4);
            short4v pk;
#pragma unroll
            for (int j = 0; j < 4; j++) pk[j] = (short)f2bf((vals[i][j] - mu) * rs * g4[j] + be4[j]);
            int bo = (a * 1024 + chunk * 8) ^ ((a & 7) << 4);
            *(short4v*)((char*)ctxin + bo) = pk;
        }
    }

    __syncthreads();

    // ---- phase 1: GEMM Uv & Vv.  A: [96 x 256] LDS; B: packed global, prefetched. ----
    floatx4 accU[3][2][2], accV[3][2][2];   // [d][g(atom half)][cf]
#pragma unroll
    for (int d = 0; d < 3; d++)
#pragma unroll
        for (int g = 0; g < 2; g++)
#pragma unroll
            for (int cf = 0; cf < 2; cf++) { accU[d][g][cf] = (floatx4)0.f; accV[d][g][cf] = (floatx4)0.f; }

    {
        const short8* PU = (const short8*)(P);
        const short8* PV = (const short8*)(P + 65536);
        short8 bU[2][2], bV[2][2];
#pragma unroll
        for (int cf = 0; cf < 2; cf++) {
            int nb = (w << 1) + cf;
            bU[0][cf] = PU[(size_t)(nb * 8) * 64 + l];
            bV[0][cf] = PV[(size_t)(nb * 8) * 64 + l];
        }
#pragma unroll
        for (int ks = 0; ks < 8; ks++) {
            int cur = ks & 1, nxt = cur ^ 1;
            if (ks < 7) {
#pragma unroll
                for (int cf = 0; cf < 2; cf++) {
                    int nb = (w << 1) + cf;
                    bU[nxt][cf] = PU[(size_t)(nb * 8 + ks + 1) * 64 + l];
                    bV[nxt][cf] = PV[(size_t)(nb * 8 + ks + 1) * 64 + l];
                }
            }
            short8 afr[3][2];
#pragma unroll
            for (int d = 0; d < 3; d++)
#pragma unroll
                for (int g = 0; g < 2; g++) {
                    int r = d * 32 + g * 16 + l15;
                    int bo = (r * 512 + (ks << 6) + (lhi << 4)) ^ ((r & 7) << 4);
                    afr[d][g] = *(const short8*)((const char*)A_buf + bo);
                }
#pragma unroll
            for (int cf = 0; cf < 2; cf++)
#pragma unroll
                for (int d = 0; d < 3; d++)
#pragma unroll
                    for (int g = 0; g < 2; g++) {
                        accU[d][g][cf] = __builtin_amdgcn_mfma_f32_16x16x32_bf16(afr[d][g], bU[cur][cf], accU[d][g][cf], 0, 0, 0);
                        accV[d][g][cf] = __builtin_amdgcn_mfma_f32_16x16x32_bf16(afr[d][g], bV[cur][cf], accV[d][g][cf], 0, 0, 0);
                    }
        }
    }

    // ---- dot_uv (regs) and ||Vv|| -> ctxin[:,256:512] ----
    float dotv[2][2][4];
#pragma unroll
    for (int g = 0; g < 2; g++)
#pragma unroll
        for (int cf = 0; cf < 2; cf++)
#pragma unroll
            for (int j = 0; j < 4; j++) {
                float du = accU[0][g][cf][j] * accV[0][g][cf][j] + accU[1][g][cf][j] * accV[1][g][cf][j]
                         + accU[2][g][cf][j] * accV[2][g][cf][j];
                dotv[g][cf][j] = du;
                float nv = sqrtf(accV[0][g][cf][j] * accV[0][g][cf][j] + accV[1][g][cf][j] * accV[1][g][cf][j]
                               + accV[2][g][cf][j] * accV[2][g][cf][j] + 1e-8f);
                int a = (g << 4) + (lhi << 2) + j;
                int c = (w << 5) + (cf << 4) + l15;
                int bo = (a * 1024 + (256 + c) * 2) ^ ((a & 7) << 4);
                *(unsigned short*)((char*)ctxin + bo) = f2bf(nv);
            }

    __syncthreads();

    // ---- phase 2: hidden = silu(ctx_in @ W1 + b1), M=32, K=512 -> hid in A_buf ----
    {
        floatx4 acc2[2][2];
#pragma unroll
        for (int g = 0; g < 2; g++)
#pragma unroll
            for (int cf = 0; cf < 2; cf++) acc2[g][cf] = (floatx4)0.f;
        const short8* PW1 = (const short8*)(P + 131072);
        short8 bw[2][2];
#pragma unroll
        for (int cf = 0; cf < 2; cf++) {
            int nb = (w << 1) + cf;
            bw[0][cf] = PW1[(size_t)(nb * 16) * 64 + l];
        }
#pragma unroll
        for (int ks = 0; ks < 16; ks++) {
            int cur = ks & 1, nxt = cur ^ 1;
            if (ks < 15) {
#pragma unroll
                for (int cf = 0; cf < 2; cf++) {
                    int nb = (w << 1) + cf;
                    bw[nxt][cf] = PW1[(size_t)(nb * 16 + ks + 1) * 64 + l];
                }
            }
            short8 af[2];
#pragma unroll
            for (int g = 0; g < 2; g++) {
                int ar = g * 16 + l15;
                int bo = (ar * 1024 + (ks << 6) + (lhi << 4)) ^ ((ar & 7) << 4);
                af[g] = *(const short8*)((const char*)ctxin + bo);
            }
#pragma unroll
            for (int cf = 0; cf < 2; cf++)
#pragma unroll
                for (int g = 0; g < 2; g++)
                    acc2[g][cf] = __builtin_amdgcn_mfma_f32_16x16x32_bf16(af[g], bw[cur][cf], acc2[g][cf], 0, 0, 0);
        }
#pragma unroll
        for (int cf = 0; cf < 2; cf++) {
            int c = (w << 5) + (cf << 4) + l15;
            float bb = b1[c];
#pragma unroll
            for (int g = 0; g < 2; g++)
#pragma unroll
                for (int j = 0; j < 4; j++) {
                    int a = (g << 4) + (lhi << 2) + j;
                    float x = acc2[g][cf][j] + bb;
                    float hh = x / (1.f + expf(-x));
                    int bo = (a * 512 + c * 2) ^ ((a & 7) << 4);
                    *(unsigned short*)((char*)A_buf + bo) = f2bf(hh);
                }
        }
    }

    __syncthreads();

    // ---- phase 3: ctx = hidden @ W2 + b2, M=32, K=256, N=768; wave owns matched strips ----
    floatx4 acc3[3][2][2];   // [seg(ss,sv,vv)][g][cf]
#pragma unroll
    for (int sg = 0; sg < 3; sg++)
#pragma unroll
        for (int g = 0; g < 2; g++)
#pragma unroll
            for (int cf = 0; cf < 2; cf++) acc3[sg][g][cf] = (floatx4)0.f;
    {
        const short8* PW2 = (const short8*)(P + 262144);
        short8 bw[2][6];
#pragma unroll
        for (int sg = 0; sg < 3; sg++)
#pragma unroll
            for (int cf = 0; cf < 2; cf++) {
                int nb = sg * 16 + (w << 1) + cf;
                bw[0][sg * 2 + cf] = PW2[(size_t)(nb * 8) * 64 + l];
            }
#pragma unroll
        for (int ks = 0; ks < 8; ks++) {
            int cur = ks & 1, nxt = cur ^ 1;
            if (ks < 7) {
#pragma unroll
                for (int sg = 0; sg < 3; sg++)
#pragma unroll
                    for (int cf = 0; cf < 2; cf++) {
                        int nb = sg * 16 + (w << 1) + cf;
                        bw[nxt][sg * 2 + cf] = PW2[(size_t)(nb * 8 + ks + 1) * 64 + l];
                    }
            }
            short8 af[2];
#pragma unroll
            for (int g = 0; g < 2; g++) {
                int ar = g * 16 + l15;
                int bo = (ar * 512 + (ks << 6) + (lhi << 4)) ^ ((ar & 7) << 4);
                af[g] = *(const short8*)((const char*)A_buf + bo);
            }
#pragma unroll
            for (int sg = 0; sg < 3; sg++)
#pragma unroll
                for (int cf = 0; cf < 2; cf++)
#pragma unroll
                    for (int g = 0; g < 2; g++)
                        acc3[sg][g][cf] = __builtin_amdgcn_mfma_f32_16x16x32_bf16(af[g], bw[cur][sg * 2 + cf], acc3[sg][g][cf], 0, 0, 0);
        }
    }

    // ---- epilogue: fully in registers ----
#pragma unroll
    for (int g = 0; g < 2; g++)
#pragma unroll
        for (int cf = 0; cf < 2; cf++) {
            int c = (w << 5) + (cf << 4) + l15;
            float bss = b2[c], bsv = b2[256 + c], bvv = b2[512 + c];
#pragma unroll
            for (int j = 0; j < 4; j++) {
                int a = (g << 4) + (lhi << 2) + j;
                size_t grow = (size_t)(atom0 + a);
                size_t gi = grow * H + c;
                float a_ss = acc3[0][g][cf][j] + bss;
                float a_sv = acc3[1][g][cf][j] + bsv;
                float a_vv = acc3[2][g][cf][j] + bvv;
                s_out[gi] = s[gi] + a_ss + a_sv * dotv[g][cf][j];
#pragma unroll
                for (int d = 0; d < 3; d++) {
                    size_t vi = (grow * 3 + d) * (size_t)H + c;
                    v_out[vi] = v[vi] + a_vv * accU[d][g][cf][j];
                }
            }
        }
}

extern "C" void kernel_launch(void* const* d_in, const int* in_sizes, int n_in,
                              void* d_out, int out_size, void* d_ws, size_t ws_size,
                              hipStream_t stream) {
    const float* s     = (const float*)d_in[0];
    const float* v     = (const float*)d_in[1];
    const float* gamma = (const float*)d_in[2];
    const float* beta  = (const float*)d_in[3];
    const float* U_W   = (const float*)d_in[4];
    const float* V_W   = (const float*)d_in[5];
    const float* W1    = (const float*)d_in[6];
    const float* b1    = (const float*)d_in[7];
    const float* W2    = (const float*)d_in[8];
    const float* b2    = (const float*)d_in[9];
    float* s_out = (float*)d_out;
    float* v_out = s_out + (size_t)NATOMS * H;
    unsigned short* P = (unsigned short*)d_ws;   // needs 917504 B

    pack_weights<<<dim3(224), dim3(256), 0, stream>>>(U_W, V_W, W1, W2, P);
    painn_main<<<dim3(NATOMS / MB), dim3(512), 0, stream>>>(s, v, gamma, beta, b1, b2, P, s_out, v_out);
}

// Round 3
// 422.081 us; speedup vs baseline: 2.3332x; 1.0604x over previous
//
#include <hip/hip_runtime.h>
#include <stdint.h>

#define H 256
#define NATOMS 100000
#define MB 32

typedef float floatx4 __attribute__((ext_vector_type(4)));
typedef short short8 __attribute__((ext_vector_type(8)));
typedef short short4v __attribute__((ext_vector_type(4)));

__device__ __forceinline__ unsigned short f2bf(float x) {
    union { float f; uint32_t u; } c; c.f = x;
    return (unsigned short)((c.u + 0x7FFFu + ((c.u >> 16) & 1u)) >> 16);
}
__device__ __forceinline__ float bf2f(unsigned short h) {
    union { uint32_t u; float f; } c; c.u = ((uint32_t)h) << 16; return c.f;
}

// ---------------------------------------------------------------------------
// Pack weights (f32 [K][N] row-major) into bf16 MFMA-B-fragment order:
// frag (kb, nb): P[(fragBase + fl)*512 + l*8 + e] = W[kb*32 + (l>>4)*8 + e][nb*16 + (l&15)]
// fl = nb*(K/32) + kb.
// Layout in ws (bf16 elems): U@0, V@65536, W1@131072, W2@262144.
// ---------------------------------------------------------------------------
__global__ void pack_weights(const float* __restrict__ U_W, const float* __restrict__ V_W,
                             const float* __restrict__ W1, const float* __restrict__ W2,
                             unsigned short* __restrict__ P) {
    int gtid = blockIdx.x * 256 + threadIdx.x;
    int fid = gtid >> 6, l = gtid & 63;
    const float* src; int K, N, fl; unsigned short* dst;
    if (fid < 128)      { src = U_W; K = 256; N = 256; fl = fid;       dst = P; }
    else if (fid < 256) { src = V_W; K = 256; N = 256; fl = fid - 128; dst = P + 65536; }
    else if (fid < 512) { src = W1;  K = 512; N = 256; fl = fid - 256; dst = P + 131072; }
    else                { src = W2;  K = 256; N = 768; fl = fid - 512; dst = P + 262144; }
    int kbc = K >> 5;
    int nb = fl / kbc, kb = fl - nb * kbc;
    int k0 = kb * 32 + ((l >> 4) << 3);
    int n0 = nb * 16 + (l & 15);
    short8 outv;
#pragma unroll
    for (int e = 0; e < 8; e++) outv[e] = (short)f2bf(src[(size_t)(k0 + e) * N + n0]);
    *(short8*)(dst + (size_t)fl * 512 + l * 8) = outv;
}

// ---------------------------------------------------------------------------
// Fused PaiNN mixing: one block = 32 atoms, 1024 threads (16 waves).
// Wave w owns output-channel strip [16w, 16w+16) of each segment.
// LDS: A_buf 48KB (v tile, stays live), ctxin 32KB, hid 16KB, stile 16KB = 112KB.
// One block/CU, 16 waves => 4 waves/SIMD.
// ---------------------------------------------------------------------------
__global__ __launch_bounds__(1024, 4) void painn_main(
    const float* __restrict__ s, const float* __restrict__ v,
    const float* __restrict__ gamma, const float* __restrict__ beta,
    const float* __restrict__ b1, const float* __restrict__ b2,
    const unsigned short* __restrict__ P,
    float* __restrict__ s_out, float* __restrict__ v_out) {

    __shared__ unsigned short A_buf[96 * 256];   // v tile bf16, rows r=d*32+a, swizzled
    __shared__ unsigned short ctxin[32 * 512];   // [a][0:256]=s_normed, [256:512]=Vv_norm
    __shared__ unsigned short hid[32 * 256];     // silu(ctx_in@W1+b1)
    __shared__ unsigned short stile[32 * 256];   // raw s (bf16) for epilogue

    const int tid = threadIdx.x;
    const int w = tid >> 6, l = tid & 63;
    const int l15 = l & 15, lhi = l >> 4;
    const int atom0 = blockIdx.x * MB;

    // ---- phase 0a: stage v tile -> LDS bf16, swizzled ----
    {
        const floatx4* vsrc = (const floatx4*)(v + (size_t)atom0 * 3 * H);
#pragma unroll
        for (int i = 0; i < 6; i++) {
            int q = i * 1024 + tid;           // float4 index, 6144 total
            int g = q >> 6, c4 = q & 63;
            floatx4 val = vsrc[q];
            int a = g / 3, d = g - 3 * a;
            int r = d * 32 + a;
            short4v pk;
#pragma unroll
            for (int j = 0; j < 4; j++) pk[j] = (short)f2bf(val[j]);
            int bo = (r * 512 + c4 * 8) ^ ((r & 7) << 4);
            *(short4v*)((char*)A_buf + bo) = pk;
        }
    }

    // ---- phase 0b: LayerNorm(s) -> ctxin[:,0:256]; raw s -> stile ----
    {
        int a = tid >> 5, lg = tid & 31;      // 32 lanes per atom
        const floatx4* srow = (const floatx4*)(s + (size_t)(atom0 + a) * H);
        floatx4 vals[2];
        float sum = 0.f, sumsq = 0.f;
#pragma unroll
        for (int i = 0; i < 2; i++) {
            vals[i] = srow[lg + (i << 5)];
#pragma unroll
            for (int j = 0; j < 4; j++) { sum += vals[i][j]; sumsq += vals[i][j] * vals[i][j]; }
        }
#pragma unroll
        for (int m = 1; m < 32; m <<= 1) { sum += __shfl_xor(sum, m); sumsq += __shfl_xor(sumsq, m); }
        float mu = sum * (1.f / 256.f);
        float var = sumsq * (1.f / 256.f) - mu * mu;
        float rs = rsqrtf(var + 1e-5f);
#pragma unroll
        for (int i = 0; i < 2; i++) {
            int chunk = lg + (i << 5);
            floatx4 g4 = *(const floatx4*)(gamma + chunk * 4);
            floatx4 be4 = *(const floatx4*)(beta + chunk * 4);
            short4v pk, pr;
#pragma unroll
            for (int j = 0; j < 4; j++) {
                pk[j] = (short)f2bf((vals[i][j] - mu) * rs * g4[j] + be4[j]);
                pr[j] = (short)f2bf(vals[i][j]);
            }
            int bo = (a * 1024 + chunk * 8) ^ ((a & 7) << 4);
            *(short4v*)((char*)ctxin + bo) = pk;
            int bo2 = (a * 512 + chunk * 8) ^ ((a & 7) << 4);
            *(short4v*)((char*)stile + bo2) = pr;
        }
    }

    __syncthreads();

    // ---- phase 1: GEMM Uv & Vv.  A: [96 x 256] LDS; B: packed global (L2), ping-pong. ----
    floatx4 accU[3][2], accV[3][2];           // [d][g(atom half)]
#pragma unroll
    for (int d = 0; d < 3; d++)
#pragma unroll
        for (int g = 0; g < 2; g++) { accU[d][g] = (floatx4)0.f; accV[d][g] = (floatx4)0.f; }

    {
        const short8* PU = (const short8*)(P);
        const short8* PV = (const short8*)(P + 65536);
        short8 bU[2], bV[2];
        bU[0] = PU[(size_t)(w * 8) * 64 + l];
        bV[0] = PV[(size_t)(w * 8) * 64 + l];
#pragma unroll
        for (int ks = 0; ks < 8; ks++) {
            int cur = ks & 1, nxt = cur ^ 1;
            if (ks < 7) {
                bU[nxt] = PU[(size_t)(w * 8 + ks + 1) * 64 + l];
                bV[nxt] = PV[(size_t)(w * 8 + ks + 1) * 64 + l];
            }
            short8 afr[3][2];
#pragma unroll
            for (int d = 0; d < 3; d++)
#pragma unroll
                for (int g = 0; g < 2; g++) {
                    int r = d * 32 + g * 16 + l15;
                    int bo = (r * 512 + (ks << 6) + (lhi << 4)) ^ ((r & 7) << 4);
                    afr[d][g] = *(const short8*)((const char*)A_buf + bo);
                }
#pragma unroll
            for (int d = 0; d < 3; d++)
#pragma unroll
                for (int g = 0; g < 2; g++) {
                    accU[d][g] = __builtin_amdgcn_mfma_f32_16x16x32_bf16(afr[d][g], bU[cur], accU[d][g], 0, 0, 0);
                    accV[d][g] = __builtin_amdgcn_mfma_f32_16x16x32_bf16(afr[d][g], bV[cur], accV[d][g], 0, 0, 0);
                }
        }
    }

    // ---- dot_uv (regs) and ||Vv|| -> ctxin[:,256:512] ----
    float dotv[2][4];
#pragma unroll
    for (int g = 0; g < 2; g++)
#pragma unroll
        for (int j = 0; j < 4; j++) {
            float du = accU[0][g][j] * accV[0][g][j] + accU[1][g][j] * accV[1][g][j]
                     + accU[2][g][j] * accV[2][g][j];
            dotv[g][j] = du;
            float nv = sqrtf(accV[0][g][j] * accV[0][g][j] + accV[1][g][j] * accV[1][g][j]
                           + accV[2][g][j] * accV[2][g][j] + 1e-8f);
            int a = (g << 4) + (lhi << 2) + j;
            int c = (w << 4) + l15;
            int bo = (a * 1024 + (256 + c) * 2) ^ ((a & 7) << 4);
            *(unsigned short*)((char*)ctxin + bo) = f2bf(nv);
        }

    __syncthreads();

    // ---- phase 2: hidden = silu(ctx_in @ W1 + b1), M=32, K=512 -> hid ----
    {
        floatx4 acc2[2];
#pragma unroll
        for (int g = 0; g < 2; g++) acc2[g] = (floatx4)0.f;
        const short8* PW1 = (const short8*)(P + 131072);
        short8 bw[2];
        bw[0] = PW1[(size_t)(w * 16) * 64 + l];
#pragma unroll
        for (int ks = 0; ks < 16; ks++) {
            int cur = ks & 1, nxt = cur ^ 1;
            if (ks < 15) bw[nxt] = PW1[(size_t)(w * 16 + ks + 1) * 64 + l];
            short8 af[2];
#pragma unroll
            for (int g = 0; g < 2; g++) {
                int ar = g * 16 + l15;
                int bo = (ar * 1024 + (ks << 6) + (lhi << 4)) ^ ((ar & 7) << 4);
                af[g] = *(const short8*)((const char*)ctxin + bo);
            }
#pragma unroll
            for (int g = 0; g < 2; g++)
                acc2[g] = __builtin_amdgcn_mfma_f32_16x16x32_bf16(af[g], bw[cur], acc2[g], 0, 0, 0);
        }
        int c = (w << 4) + l15;
        float bb = b1[c];
#pragma unroll
        for (int g = 0; g < 2; g++)
#pragma unroll
            for (int j = 0; j < 4; j++) {
                int a = (g << 4) + (lhi << 2) + j;
                float x = acc2[g][j] + bb;
                float hh = x / (1.f + expf(-x));
                int bo = (a * 512 + c * 2) ^ ((a & 7) << 4);
                *(unsigned short*)((char*)hid + bo) = f2bf(hh);
            }
    }

    __syncthreads();

    // ---- phase 3: ctx = hidden @ W2 + b2, M=32, K=256, N=768; matched strips ----
    floatx4 acc3[3][2];   // [seg(ss,sv,vv)][g]
#pragma unroll
    for (int sg = 0; sg < 3; sg++)
#pragma unroll
        for (int g = 0; g < 2; g++) acc3[sg][g] = (floatx4)0.f;
    {
        const short8* PW2 = (const short8*)(P + 262144);
        short8 bw[2][3];
#pragma unroll
        for (int sg = 0; sg < 3; sg++)
            bw[0][sg] = PW2[(size_t)((sg * 16 + w) * 8) * 64 + l];
#pragma unroll
        for (int ks = 0; ks < 8; ks++) {
            int cur = ks & 1, nxt = cur ^ 1;
            if (ks < 7) {
#pragma unroll
                for (int sg = 0; sg < 3; sg++)
                    bw[nxt][sg] = PW2[(size_t)((sg * 16 + w) * 8 + ks + 1) * 64 + l];
            }
            short8 af[2];
#pragma unroll
            for (int g = 0; g < 2; g++) {
                int ar = g * 16 + l15;
                int bo = (ar * 512 + (ks << 6) + (lhi << 4)) ^ ((ar & 7) << 4);
                af[g] = *(const short8*)((const char*)hid + bo);
            }
#pragma unroll
            for (int sg = 0; sg < 3; sg++)
#pragma unroll
                for (int g = 0; g < 2; g++)
                    acc3[sg][g] = __builtin_amdgcn_mfma_f32_16x16x32_bf16(af[g], bw[cur][sg], acc3[sg][g], 0, 0, 0);
        }
    }

    // ---- epilogue: fully from registers + LDS tiles (no global re-reads) ----
    {
        int c = (w << 4) + l15;
        float bss = b2[c], bsv = b2[256 + c], bvv = b2[512 + c];
#pragma unroll
        for (int g = 0; g < 2; g++)
#pragma unroll
            for (int j = 0; j < 4; j++) {
                int a = (g << 4) + (lhi << 2) + j;
                size_t grow = (size_t)(atom0 + a);
                float a_ss = acc3[0][g][j] + bss;
                float a_sv = acc3[1][g][j] + bsv;
                float a_vv = acc3[2][g][j] + bvv;
                float sraw = bf2f(*(const unsigned short*)((const char*)stile + ((a * 512 + c * 2) ^ ((a & 7) << 4))));
                s_out[grow * H + c] = sraw + a_ss + a_sv * dotv[g][j];
#pragma unroll
                for (int d = 0; d < 3; d++) {
                    int r = d * 32 + a;
                    float vv = bf2f(*(const unsigned short*)((const char*)A_buf + ((r * 512 + c * 2) ^ ((r & 7) << 4))));
                    v_out[(grow * 3 + d) * (size_t)H + c] = vv + a_vv * accU[d][g][j];
                }
            }
    }
}

extern "C" void kernel_launch(void* const* d_in, const int* in_sizes, int n_in,
                              void* d_out, int out_size, void* d_ws, size_t ws_size,
                              hipStream_t stream) {
    const float* s     = (const float*)d_in[0];
    const float* v     = (const float*)d_in[1];
    const float* gamma = (const float*)d_in[2];
    const float* beta  = (const float*)d_in[3];
    const float* U_W   = (const float*)d_in[4];
    const float* V_W   = (const float*)d_in[5];
    const float* W1    = (const float*)d_in[6];
    const float* b1    = (const float*)d_in[7];
    const float* W2    = (const float*)d_in[8];
    const float* b2    = (const float*)d_in[9];
    float* s_out = (float*)d_out;
    float* v_out = s_out + (size_t)NATOMS * H;
    unsigned short* P = (unsigned short*)d_ws;   // needs 917504 B

    pack_weights<<<dim3(224), dim3(256), 0, stream>>>(U_W, V_W, W1, W2, P);
    painn_main<<<dim3(NATOMS / MB), dim3(1024), 0, stream>>>(s, v, gamma, beta, b1, b2, P, s_out, v_out);
}